// Round 4
// baseline (2455.732 us; speedup 1.0000x reference)
//
#include <hip/hip_runtime.h>
#include <hip/hip_bf16.h>

#define B_ 512
#define T_ 128
#define DIN_ 256
#define H_ 512
#define KPAD 1048          // LDS weight row stride (bf16): 524 dwords -> 2-way max conflict
#define WROWS 48           // 3 gates x 16 j
#define CPAD 52            // combine buffer row stride (f32)
#define HS ((size_t)B_ * H_)
#define OUT_MAIN ((size_t)B_ * T_ * H_)

typedef __attribute__((ext_vector_type(8))) short short8;
typedef __attribute__((ext_vector_type(4))) float f32x4;

__device__ __forceinline__ float sigm(float v) { return 1.0f / (1.0f + __expf(-v)); }

__device__ __forceinline__ unsigned short f2bf(float f) {
    union { __hip_bfloat16 b; unsigned short u; } c;
    c.b = __float2bfloat16(f);
    return c.u;
}

__device__ __forceinline__ short8 cvt8v(f32x4 u, f32x4 v) {
    short8 o;
    o[0] = (short)f2bf(u[0]); o[1] = (short)f2bf(u[1]);
    o[2] = (short)f2bf(u[2]); o[3] = (short)f2bf(u[3]);
    o[4] = (short)f2bf(v[0]); o[5] = (short)f2bf(v[1]);
    o[6] = (short)f2bf(v[2]); o[7] = (short)f2bf(v[3]);
    return o;
}

// 16B of h-state via two 8B agent-scope atomic loads (coherent point, no fences).
__device__ __forceinline__ short8 load_h16(const __hip_bfloat16* p) {
    union { unsigned long long u[2]; short8 v; } r;
    r.u[0] = __hip_atomic_load((const unsigned long long*)p,       __ATOMIC_RELAXED, __HIP_MEMORY_SCOPE_AGENT);
    r.u[1] = __hip_atomic_load((const unsigned long long*)(p + 4), __ATOMIC_RELAXED, __HIP_MEMORY_SCOPE_AGENT);
    return r.v;
}

__device__ __forceinline__ void store_h8(__hip_bfloat16* p, const float* h4) {
    union { unsigned short s[4]; unsigned long long u; } r;
    r.s[0] = f2bf(h4[0]); r.s[1] = f2bf(h4[1]);
    r.s[2] = f2bf(h4[2]); r.s[3] = f2bf(h4[3]);
    __hip_atomic_store((unsigned long long*)p, r.u, __ATOMIC_RELAXED, __HIP_MEMORY_SCOPE_AGENT);
}

__global__ void init_kernel(const float* __restrict__ h_in,
                            __hip_bfloat16* __restrict__ h0b,
                            __hip_bfloat16* __restrict__ h1b,
                            int* __restrict__ flags)
{
    int i = blockIdx.x * blockDim.x + threadIdx.x;
    if (i < 512) flags[i] = 0;
    if (i < (int)(B_ * H_)) {
        int b = i >> 9, j = i & (H_ - 1);
        h0b[HS + i] = __float2bfloat16(h_in[((size_t)b * 2 + 0) * H_ + j]);
        h1b[HS + i] = __float2bfloat16(h_in[((size_t)b * 2 + 1) * H_ + j]);
    }
}

// One k-chunk (32 wide) of the 3-gate MFMA group. WIDX = LDS word offset of chunk.
#define MF3(WIDX, A0, A1) { \
    short8 wf0 = *(const short8*)&wlds[(0 * 16 + l15) * KPAD + (WIDX)]; \
    short8 wf1 = *(const short8*)&wlds[(1 * 16 + l15) * KPAD + (WIDX)]; \
    short8 wf2 = *(const short8*)&wlds[(2 * 16 + l15) * KPAD + (WIDX)]; \
    acc[0][0] = __builtin_amdgcn_mfma_f32_16x16x32_bf16(wf0, A0, acc[0][0], 0, 0, 0); \
    acc[1][0] = __builtin_amdgcn_mfma_f32_16x16x32_bf16(wf0, A1, acc[1][0], 0, 0, 0); \
    acc[0][1] = __builtin_amdgcn_mfma_f32_16x16x32_bf16(wf1, A0, acc[0][1], 0, 0, 0); \
    acc[1][1] = __builtin_amdgcn_mfma_f32_16x16x32_bf16(wf1, A1, acc[1][1], 0, 0, 0); \
    acc[0][2] = __builtin_amdgcn_mfma_f32_16x16x32_bf16(wf2, A0, acc[0][2], 0, 0, 0); \
    acc[1][2] = __builtin_amdgcn_mfma_f32_16x16x32_bf16(wf2, A1, acc[1][2], 0, 0, 0); }

// Persistent kernel. 256 blocks x 512 threads, 1 block/CU (LDS-forced).
// block -> (layer l, batch-tile bt of 128 rows, j-tile jt of 16 cols)
// waves: mq 0..3 (32 batch rows each) x part (0 = input-side GEMM, 1 = hidden-side GEMM)
// Swapped MFMA: D[j][b] = mfma(W_frag, act_frag) -> lane holds 4 consecutive j for one b.
__global__ __launch_bounds__(512) void gru_persist(
    const float* __restrict__ x, const int* __restrict__ is_init,
    const float* __restrict__ h_in,
    const float* __restrict__ wih0, const float* __restrict__ whh0,
    const float* __restrict__ bih0, const float* __restrict__ bhh0,
    const float* __restrict__ wih1, const float* __restrict__ whh1,
    const float* __restrict__ bih1, const float* __restrict__ bhh1,
    __hip_bfloat16* __restrict__ h0b, __hip_bfloat16* __restrict__ h1b,
    int* __restrict__ flags, float* __restrict__ out)
{
    __shared__ __hip_bfloat16 wlds[WROWS * KPAD];   // 100608 B
    __shared__ float cmb[128 * CPAD];               //  26624 B

    const int bid = blockIdx.x;
    const int l   = bid >> 7;
    const int bt  = (bid >> 5) & 3;
    const int jt  = bid & 31;
    const int tid = threadIdx.x;
    const int lane = tid & 63;
    const int wid  = tid >> 6;
    const int mq   = wid >> 1;
    const int part = wid & 1;
    const int l15  = lane & 15;
    const int kg   = (lane >> 4) * 8;   // k offset within a 32-chunk
    const int qr4  = (lane >> 4) * 4;   // j-quad base within 16
    const int rb   = bt * 128 + mq * 32;
    const int j4   = jt * 16 + qr4;

    const float* Wi = l ? wih1 : wih0;
    const float* Wh = l ? whh1 : whh0;
    const float* bi = l ? bih1 : bih0;
    const float* bh = l ? bhh1 : bhh0;
    const int KI = l ? H_ : DIN_;

    // ---- stage weight slice to LDS (f32 -> bf16), once ----
    {
        const int nci = KI / 8;
        for (int idx = tid; idx < WROWS * nci; idx += 512) {
            int r = idx / nci, c8 = idx - r * nci;
            int grow = (r >> 4) * H_ + jt * 16 + (r & 15);
            const float* p = Wi + (size_t)grow * KI + c8 * 8;
            *(short8*)&wlds[r * KPAD + c8 * 8] = cvt8v(*(const f32x4*)p, *(const f32x4*)(p + 4));
        }
        for (int idx = tid; idx < WROWS * 64; idx += 512) {
            int r = idx >> 6, c8 = idx & 63;
            int grow = (r >> 4) * H_ + jt * 16 + (r & 15);
            const float* p = Wh + (size_t)grow * H_ + c8 * 8;
            *(short8*)&wlds[r * KPAD + KI + c8 * 8] = cvt8v(*(const f32x4*)p, *(const f32x4*)(p + 4));
        }
    }

    // ---- hoisted per-lane constants ----
    const f32x4 b_r  = *(const f32x4*)&bi[j4]          + *(const f32x4*)&bh[j4];
    const f32x4 b_z  = *(const f32x4*)&bi[H_ + j4]     + *(const f32x4*)&bh[H_ + j4];
    const f32x4 b_in = *(const f32x4*)&bi[2 * H_ + j4];
    const f32x4 b_hn = *(const f32x4*)&bh[2 * H_ + j4];

    f32x4 hp[2];   // f32 master state: rows rb + mm*16 + l15, cols j4..j4+3
    #pragma unroll
    for (int mm = 0; mm < 2; ++mm)
        hp[mm] = *(const f32x4*)&h_in[((size_t)(rb + mm * 16 + l15) * 2 + l) * H_ + j4];

    __syncthreads();

    const short8 zed = {0, 0, 0, 0, 0, 0, 0, 0};

    for (int t = 0; t <= T_; ++t) {
        if (l == 0 && t == T_) break;         // l0 has no work in the last slot
        const int s = l ? (t - 1) : t;
        const bool active = (s >= 0);

        f32x4 acc[2][3];
        #pragma unroll
        for (int mm = 0; mm < 2; ++mm)
            #pragma unroll
            for (int g = 0; g < 3; ++g)
                acc[mm][g] = f32x4{0.f, 0.f, 0.f, 0.f};

        // ---- pre-wait work: l0 input GEMM (x, no dependencies) ----
        if (l == 0 && part == 0) {
            const float* xr0 = x + ((size_t)(rb + l15) * T_ + s) * DIN_ + kg;
            const float* xr1 = x + ((size_t)(rb + 16 + l15) * T_ + s) * DIN_ + kg;
            f32x4 xa[2][4], xb[2][4];
            #pragma unroll
            for (int c = 0; c < 2; ++c) {
                xa[0][2*c] = *(const f32x4*)(xr0 + c*32); xa[0][2*c+1] = *(const f32x4*)(xr0 + c*32 + 4);
                xa[1][2*c] = *(const f32x4*)(xr1 + c*32); xa[1][2*c+1] = *(const f32x4*)(xr1 + c*32 + 4);
            }
            #pragma unroll
            for (int c = 0; c < 2; ++c) {
                xb[0][2*c] = *(const f32x4*)(xr0 + (2+c)*32); xb[0][2*c+1] = *(const f32x4*)(xr0 + (2+c)*32 + 4);
                xb[1][2*c] = *(const f32x4*)(xr1 + (2+c)*32); xb[1][2*c+1] = *(const f32x4*)(xr1 + (2+c)*32 + 4);
            }
            #pragma unroll
            for (int c = 0; c < 2; ++c) {
                short8 a0 = cvt8v(xa[0][2*c], xa[0][2*c+1]);
                short8 a1 = cvt8v(xa[1][2*c], xa[1][2*c+1]);
                MF3(c*32 + kg, a0, a1);
            }
            #pragma unroll
            for (int c = 0; c < 2; ++c) {
                xa[0][2*c] = *(const f32x4*)(xr0 + (4+c)*32); xa[0][2*c+1] = *(const f32x4*)(xr0 + (4+c)*32 + 4);
                xa[1][2*c] = *(const f32x4*)(xr1 + (4+c)*32); xa[1][2*c+1] = *(const f32x4*)(xr1 + (4+c)*32 + 4);
            }
            #pragma unroll
            for (int c = 0; c < 2; ++c) {
                short8 a0 = cvt8v(xb[0][2*c], xb[0][2*c+1]);
                short8 a1 = cvt8v(xb[1][2*c], xb[1][2*c+1]);
                MF3((2+c)*32 + kg, a0, a1);
            }
            #pragma unroll
            for (int c = 0; c < 2; ++c) {
                xb[0][2*c] = *(const f32x4*)(xr0 + (6+c)*32); xb[0][2*c+1] = *(const f32x4*)(xr0 + (6+c)*32 + 4);
                xb[1][2*c] = *(const f32x4*)(xr1 + (6+c)*32); xb[1][2*c+1] = *(const f32x4*)(xr1 + (6+c)*32 + 4);
            }
            #pragma unroll
            for (int c = 0; c < 2; ++c) {
                short8 a0 = cvt8v(xa[0][2*c], xa[0][2*c+1]);
                short8 a1 = cvt8v(xa[1][2*c], xa[1][2*c+1]);
                MF3((4+c)*32 + kg, a0, a1);
            }
            #pragma unroll
            for (int c = 0; c < 2; ++c) {
                short8 a0 = cvt8v(xb[0][2*c], xb[0][2*c+1]);
                short8 a1 = cvt8v(xb[1][2*c], xb[1][2*c+1]);
                MF3((6+c)*32 + kg, a0, a1);
            }
            #pragma unroll
            for (int mm = 0; mm < 2; ++mm)
                #pragma unroll
                for (int g = 0; g < 3; ++g)
                    *(f32x4*)&cmb[(mq * 32 + mm * 16 + l15) * CPAD + g * 16 + qr4] = acc[mm][g];
            #pragma unroll
            for (int mm = 0; mm < 2; ++mm)
                #pragma unroll
                for (int g = 0; g < 3; ++g)
                    acc[mm][g] = f32x4{0.f, 0.f, 0.f, 0.f};   // unused afterwards for part0
        }

        // ---- group wait: per-block phase flags, 64-lane parallel poll, no RMW ----
        if (t > 0 && wid == 1) {
            const int fidx = (lane >> 5) * 128 + bt * 32 + (lane & 31);
            while (__hip_atomic_load(&flags[fidx], __ATOMIC_RELAXED, __HIP_MEMORY_SCOPE_AGENT) < t)
                __builtin_amdgcn_s_sleep(1);
        }
        __syncthreads();

        // ---- post-wait GEMMs (recurrent operands) ----
        if (active) {
            if (part == 0 && l == 1) {
                // gi over h0[s&1] (produced by l0 in previous slot)
                const __hip_bfloat16* hsrc = h0b + (size_t)(s & 1) * HS;
                const __hip_bfloat16* r0 = hsrc + (size_t)(rb + l15) * H_ + kg;
                const __hip_bfloat16* r1 = hsrc + (size_t)(rb + 16 + l15) * H_ + kg;
                short8 ha[2][4], hb[2][4];
                #pragma unroll
                for (int c = 0; c < 4; ++c) { ha[0][c] = load_h16(r0 + c*32);      ha[1][c] = load_h16(r1 + c*32); }
                #pragma unroll
                for (int c = 0; c < 4; ++c) { hb[0][c] = load_h16(r0 + (4+c)*32);  hb[1][c] = load_h16(r1 + (4+c)*32); }
                #pragma unroll
                for (int c = 0; c < 4; ++c) MF3(c*32 + kg, ha[0][c], ha[1][c]);
                #pragma unroll
                for (int c = 0; c < 4; ++c) { ha[0][c] = load_h16(r0 + (8+c)*32);  ha[1][c] = load_h16(r1 + (8+c)*32); }
                #pragma unroll
                for (int c = 0; c < 4; ++c) MF3((4+c)*32 + kg, hb[0][c], hb[1][c]);
                #pragma unroll
                for (int c = 0; c < 4; ++c) { hb[0][c] = load_h16(r0 + (12+c)*32); hb[1][c] = load_h16(r1 + (12+c)*32); }
                #pragma unroll
                for (int c = 0; c < 4; ++c) MF3((8+c)*32 + kg, ha[0][c], ha[1][c]);
                #pragma unroll
                for (int c = 0; c < 4; ++c) MF3((12+c)*32 + kg, hb[0][c], hb[1][c]);
                #pragma unroll
                for (int mm = 0; mm < 2; ++mm)
                    #pragma unroll
                    for (int g = 0; g < 3; ++g)
                        *(f32x4*)&cmb[(mq * 32 + mm * 16 + l15) * CPAD + g * 16 + qr4] = acc[mm][g];
            } else if (part == 1) {
                // gh over h_l[(s+1)&1], with per-row is_init zeroing
                const __hip_bfloat16* hsrc = (l ? h1b : h0b) + (size_t)((s + 1) & 1) * HS;
                const bool z0 = is_init[(rb + l15) * T_ + s] != 0;
                const bool z1 = is_init[(rb + 16 + l15) * T_ + s] != 0;
                const __hip_bfloat16* r0 = hsrc + (size_t)(rb + l15) * H_ + kg;
                const __hip_bfloat16* r1 = hsrc + (size_t)(rb + 16 + l15) * H_ + kg;
                const int wo = KI;
                short8 ha[2][4], hb[2][4];
                #pragma unroll
                for (int c = 0; c < 4; ++c) { ha[0][c] = load_h16(r0 + c*32);      ha[1][c] = load_h16(r1 + c*32); }
                #pragma unroll
                for (int c = 0; c < 4; ++c) { hb[0][c] = load_h16(r0 + (4+c)*32);  hb[1][c] = load_h16(r1 + (4+c)*32); }
                #pragma unroll
                for (int c = 0; c < 4; ++c) { short8 a0 = z0 ? zed : ha[0][c]; short8 a1 = z1 ? zed : ha[1][c]; MF3(wo + c*32 + kg, a0, a1); }
                #pragma unroll
                for (int c = 0; c < 4; ++c) { ha[0][c] = load_h16(r0 + (8+c)*32);  ha[1][c] = load_h16(r1 + (8+c)*32); }
                #pragma unroll
                for (int c = 0; c < 4; ++c) { short8 a0 = z0 ? zed : hb[0][c]; short8 a1 = z1 ? zed : hb[1][c]; MF3(wo + (4+c)*32 + kg, a0, a1); }
                #pragma unroll
                for (int c = 0; c < 4; ++c) { hb[0][c] = load_h16(r0 + (12+c)*32); hb[1][c] = load_h16(r1 + (12+c)*32); }
                #pragma unroll
                for (int c = 0; c < 4; ++c) { short8 a0 = z0 ? zed : ha[0][c]; short8 a1 = z1 ? zed : ha[1][c]; MF3(wo + (8+c)*32 + kg, a0, a1); }
                #pragma unroll
                for (int c = 0; c < 4; ++c) { short8 a0 = z0 ? zed : hb[0][c]; short8 a1 = z1 ? zed : hb[1][c]; MF3(wo + (12+c)*32 + kg, a0, a1); }
            }
        }

        __syncthreads();   // gi combine visible to gh waves

        if (active && part == 1) {
            __hip_bfloat16* Hout = (l ? h1b : h0b) + (size_t)(s & 1) * HS;
            #pragma unroll
            for (int mm = 0; mm < 2; ++mm) {
                const int b = rb + mm * 16 + l15;
                const bool ini = is_init[b * T_ + s] != 0;
                const float* cp = &cmb[(mq * 32 + mm * 16 + l15) * CPAD + qr4];
                const f32x4 gi_r = *(const f32x4*)(cp);
                const f32x4 gi_z = *(const f32x4*)(cp + 16);
                const f32x4 gi_n = *(const f32x4*)(cp + 32);
                float hv[4];
                #pragma unroll
                for (int r = 0; r < 4; ++r) {
                    const float rr = sigm(gi_r[r] + acc[mm][0][r] + b_r[r]);
                    const float zz = sigm(gi_z[r] + acc[mm][1][r] + b_z[r]);
                    const float nn = tanhf(gi_n[r] + b_in[r] + rr * (acc[mm][2][r] + b_hn[r]));
                    const float hprev = ini ? 0.0f : hp[mm][r];
                    hv[r] = (1.0f - zz) * nn + zz * hprev;
                    hp[mm][r] = hv[r];
                }
                store_h8(&Hout[(size_t)b * H_ + j4], hv);
                if (l) {
                    *(f32x4*)&out[((size_t)b * T_ + s) * H_ + j4] = f32x4{hv[0], hv[1], hv[2], hv[3]};
                    if (s == T_ - 1)
                        *(f32x4*)&out[OUT_MAIN + ((size_t)b * 2 + 1) * H_ + j4] = f32x4{hv[0], hv[1], hv[2], hv[3]};
                } else if (s == T_ - 1) {
                    *(f32x4*)&out[OUT_MAIN + ((size_t)b * 2 + 0) * H_ + j4] = f32x4{hv[0], hv[1], hv[2], hv[3]};
                }
            }
        }

        __syncthreads();   // all stores drained (vmcnt0 per wave) before flag publish
        if (tid == 0)
            __hip_atomic_store(&flags[bid], t + 1, __ATOMIC_RELAXED, __HIP_MEMORY_SCOPE_AGENT);
    }
}

extern "C" void kernel_launch(void* const* d_in, const int* in_sizes, int n_in,
                              void* d_out, int out_size, void* d_ws, size_t ws_size,
                              hipStream_t stream) {
    (void)in_sizes; (void)n_in; (void)out_size; (void)ws_size;
    const float* x    = (const float*)d_in[0];
    const int*   isin = (const int*)d_in[1];
    const float* h_in = (const float*)d_in[2];
    const float* wih0 = (const float*)d_in[3];
    const float* whh0 = (const float*)d_in[4];
    const float* bih0 = (const float*)d_in[5];
    const float* bhh0 = (const float*)d_in[6];
    const float* wih1 = (const float*)d_in[7];
    const float* whh1 = (const float*)d_in[8];
    const float* bih1 = (const float*)d_in[9];
    const float* bhh1 = (const float*)d_in[10];
    float* out = (float*)d_out;

    char* wsb = (char*)d_ws;
    __hip_bfloat16* h0b = (__hip_bfloat16*)wsb;            // 2 x [512*512] ping-pong
    __hip_bfloat16* h1b = h0b + 2 * HS;
    int* flags = (int*)(wsb + 4 * HS * 2);                 // 256 per-block phase flags

    init_kernel<<<dim3(1024), dim3(256), 0, stream>>>(h_in, h0b, h1b, flags);

    gru_persist<<<dim3(256), dim3(512), 0, stream>>>(
        x, isin, h_in,
        wih0, whh0, bih0, bhh0,
        wih1, whh1, bih1, bhh1,
        h0b, h1b, flags, out);
}